// Round 5
// baseline (629.943 us; speedup 1.0000x reference)
//
#include <hip/hip_runtime.h>
#include <stdint.h>

#define NE 64
#define NT 2048
#define NH 512
#define NI 1024

typedef __attribute__((ext_vector_type(8))) short bf16x8;
typedef __attribute__((ext_vector_type(4))) float f32x4;

typedef const __attribute__((address_space(1))) void* gptr1_t;
typedef __attribute__((address_space(3))) void* lptr3_t;
#define GLOAD16(g, l) \
  __builtin_amdgcn_global_load_lds((gptr1_t)(const void*)(g), (lptr3_t)(void*)(l), 16, 0, 0)

static __device__ __forceinline__ uint16_t f2bf(float f) {
  uint32_t u = __builtin_bit_cast(uint32_t, f);
  u += 0x7fffu + ((u >> 16) & 1u);
  return (uint16_t)(u >> 16);
}

static __device__ __forceinline__ float gelu_erf(float v) {
  return 0.5f * v * (1.0f + erff(v * 0.7071067811865475f));
}

// ---------------------------------------------------------------------------
// cast_x: x[t_start+t][e][:] f32 -> xB[e][t][:] bf16
// ---------------------------------------------------------------------------
__global__ __launch_bounds__(256)
void cast_x(const float* __restrict__ x, uint16_t* __restrict__ xB,
            int t_start, int S) {
  const int total = S * NE * (NH / 8);
  for (int c = blockIdx.x * 256 + threadIdx.x; c < total; c += gridDim.x * 256) {
    const int hb = c & 63;
    const int e = (c >> 6) & 63;
    const int t = c >> 12;
    const float* ip = x + ((size_t)(t_start + t) * NE + e) * NH + (hb << 3);
    const f32x4 v0 = *(const f32x4*)ip;
    const f32x4 v1 = *(const f32x4*)(ip + 4);
    bf16x8 w;
#pragma unroll
    for (int u = 0; u < 4; ++u) {
      w[u] = (short)f2bf(v0[u]);
      w[u + 4] = (short)f2bf(v1[u]);
    }
    *(bf16x8*)&xB[((size_t)e * S + t) * NH + (hb << 3)] = w;
  }
}

// ---------------------------------------------------------------------------
// transpose + cast: in[e][K][N] f32 -> out[e][N][K] bf16, 64x64 tiles
// ---------------------------------------------------------------------------
__global__ __launch_bounds__(256)
void conv_tr(const float* __restrict__ in, uint16_t* __restrict__ out, int K, int N) {
  const int e = blockIdx.x;
  const int k0 = blockIdx.y << 6;
  const int n0 = blockIdx.z << 6;
  __shared__ uint16_t t[64][72];
  const int tid = threadIdx.x;
  const int r = tid >> 2;
  const int c0 = (tid & 3) << 4;
  const float* ip = in + ((size_t)e * K + k0 + r) * N + n0 + c0;
#pragma unroll
  for (int j = 0; j < 16; j += 4) {
    f32x4 v = *(const f32x4*)(ip + j);
#pragma unroll
    for (int u = 0; u < 4; ++u) t[c0 + j + u][r] = f2bf(v[u]);
  }
  __syncthreads();
  uint16_t* op = out + ((size_t)e * N + n0 + r) * K + k0 + c0;
  *(bf16x8*)op = *(const bf16x8*)&t[r][c0];
  *(bf16x8*)(op + 8) = *(const bf16x8*)&t[r][c0 + 8];
}

// ---------------------------------------------------------------------------
// 256x256x64 8-wave deep-pipelined grouped GEMM, m201-style phase regions:
//   R1 = { ds_read this phase's frags ; stage 1 half-tile ; [vmcnt @q3] }
//   barrier ; lgkmcnt(0) ; setprio(1) ; 16 MFMA ; setprio(0) ; barrier
// ds_reads issued PRE-barrier so their latency hides under other waves' MFMA.
// Buffers: A(T) in As[T&1]; B(T) in Bs[T&1].
// Stages during tile T: q0:A0(T+1) q1:A1(T+1) q2:B0(T+2) q3:B1(T+2).
// vmcnt(4) at q3 (12 loads outstanding; oldest 8 = tile T+1 complete).
// LDS swizzle (both ops): elem (r,k) at r*64 + ((k>>3)^(r&7))*8 + (k&7),
// applied on the global SOURCE address; LDS dest linear (gload_lds rule).
// ---------------------------------------------------------------------------
template <int KIT, int NTILES, int ASTR, int BSTR, bool GELU>
__global__ __launch_bounds__(512, 2)
void k_mm(const uint16_t* __restrict__ Ag, const uint16_t* __restrict__ Bg,
          void* __restrict__ outp, int t_start, int Ts) {
  const int Mt = Ts >> 8;
  const int nwg = gridDim.x;  // divisible by 8
  const int wid_ = (blockIdx.x & 7) * (nwg >> 3) + (blockIdx.x >> 3);
  const int bn = wid_ & (NTILES - 1);
  const int bm = (wid_ / NTILES) % Mt;
  const int be = wid_ / (NTILES * Mt);
  const int t0 = bm << 8, n0 = bn << 8;

  __shared__ __align__(16) uint16_t As[2][16384];  // [buf][half(2)*8192]
  __shared__ __align__(16) uint16_t Bs[2][16384];

  const int tid = threadIdx.x;
  const int lane = tid & 63;
  const int wv = tid >> 6;   // 0..7
  const int wm = wv >> 2;    // 0..1  (A half = wm)
  const int wn = wv & 3;     // 0..3  (B half = wn>>1)
  const int fr = lane & 15;
  const int fq = lane >> 4;

  const uint16_t* Abase = Ag + ((size_t)be * Ts + t0) * ASTR;
  const uint16_t* Bbase = Bg + ((size_t)be * (NTILES * 256) + n0) * BSTR;

  int aoff[2], boff[2];
#pragma unroll
  for (int s = 0; s < 2; ++s) {
    const int c = tid + (s << 9);
    const int row = c >> 3, g = c & 7;
    aoff[s] = row * ASTR + ((g ^ (row & 7)) << 3);
    boff[s] = row * BSTR + ((g ^ (row & 7)) << 3);
  }

  auto stageA = [&](int kt, int b, int h) {
    const uint16_t* src = Abase + (size_t)(h << 7) * ASTR + (kt << 6);
    char* dst = (char*)&As[b][0] + (h << 14) + (tid << 4);
    GLOAD16(src + aoff[0], dst);
    GLOAD16(src + aoff[1], dst + 8192);
  };
  auto stageB = [&](int kt, int b, int h) {
    const uint16_t* src = Bbase + (size_t)(h << 7) * BSTR + (kt << 6);
    char* dst = (char*)&Bs[b][0] + (h << 14) + (tid << 4);
    GLOAD16(src + boff[0], dst);
    GLOAD16(src + boff[1], dst + 8192);
  };

  auto ldsA = [&](int b, int mi, int ks) -> bf16x8 {
    const int r = (mi << 4) + fr;
    const int kg = ((ks << 2) + fq) ^ (fr & 7);
    return *(const bf16x8*)&As[b][(wm << 13) + (r << 6) + (kg << 3)];
  };
  auto ldsB = [&](int b, int ni, int ks) -> bf16x8 {
    const int r = ((wn & 1) << 6) + (ni << 4) + fr;
    const int kg = ((ks << 2) + fq) ^ (fr & 7);
    return *(const bf16x8*)&Bs[b][((wn >> 1) << 13) + (r << 6) + (kg << 3)];
  };

  f32x4 acc[8][4];
#pragma unroll
  for (int i = 0; i < 8; ++i)
#pragma unroll
    for (int j = 0; j < 4; ++j) acc[i][j] = (f32x4){0.f, 0.f, 0.f, 0.f};

  bf16x8 af[4][2], bfr[4][2];

#define MFMA_CLUSTER(ACCOFF, NI0)                                              \
  asm volatile("s_waitcnt lgkmcnt(0)" ::: "memory");                           \
  __builtin_amdgcn_sched_barrier(0);                                           \
  __builtin_amdgcn_s_setprio(1);                                               \
  _Pragma("unroll") for (int mi = 0; mi < 4; ++mi)                             \
      _Pragma("unroll") for (int ni = 0; ni < 2; ++ni)                         \
          _Pragma("unroll") for (int ks = 0; ks < 2; ++ks)                     \
              acc[mi + (ACCOFF)][ni + (NI0)] =                                 \
                  __builtin_amdgcn_mfma_f32_16x16x32_bf16(                     \
                      af[mi][ks], bfr[ni + (NI0)][ks],                         \
                      acc[mi + (ACCOFF)][ni + (NI0)], 0, 0, 0);                \
  __builtin_amdgcn_s_setprio(0);                                               \
  __builtin_amdgcn_s_barrier();                                                \
  __builtin_amdgcn_sched_barrier(0);

  // Prologue: tile0 A+B, tile1 B -> 12 loads; prove tile0 (oldest 8) landed.
  stageA(0, 0, 0);
  stageA(0, 0, 1);
  stageB(0, 0, 0);
  stageB(0, 0, 1);
  stageB(1, 1, 0);
  stageB(1, 1, 1);
  asm volatile("s_waitcnt vmcnt(4)" ::: "memory");
  __builtin_amdgcn_sched_barrier(0);
  __builtin_amdgcn_s_barrier();
  __builtin_amdgcn_sched_barrier(0);

  for (int T = 0; T < KIT; ++T) {
    const int rb = T & 1;
    const int c1 = (T + 1 < KIT) ? T + 1 : KIT - 1;  // A-stage tile (clamped)
    const int c2 = (T + 2 < KIT) ? T + 2 : KIT - 1;  // B-stage tile (clamped)

    // ---- q0: R1 = dsread A(0-3)+B(0-1) ; stage A0(T+1) ----
#pragma unroll
    for (int mi = 0; mi < 4; ++mi)
#pragma unroll
      for (int ks = 0; ks < 2; ++ks) af[mi][ks] = ldsA(rb, mi, ks);
#pragma unroll
    for (int ni = 0; ni < 2; ++ni)
#pragma unroll
      for (int ks = 0; ks < 2; ++ks) bfr[ni][ks] = ldsB(rb, ni, ks);
    stageA(c1, (T + 1) & 1, 0);
    __builtin_amdgcn_sched_barrier(0);
    __builtin_amdgcn_s_barrier();
    MFMA_CLUSTER(0, 0)

    // ---- q1: R1 = dsread B(2-3) ; stage A1(T+1) ----
#pragma unroll
    for (int ni = 2; ni < 4; ++ni)
#pragma unroll
      for (int ks = 0; ks < 2; ++ks) bfr[ni][ks] = ldsB(rb, ni, ks);
    stageA(c1, (T + 1) & 1, 1);
    __builtin_amdgcn_sched_barrier(0);
    __builtin_amdgcn_s_barrier();
    MFMA_CLUSTER(0, 2)

    // ---- q2: R1 = dsread A(4-7) ; stage B0(T+2) into Bs[rb] (B reads done) --
#pragma unroll
    for (int mi = 0; mi < 4; ++mi)
#pragma unroll
      for (int ks = 0; ks < 2; ++ks) af[mi][ks] = ldsA(rb, mi + 4, ks);
    stageB(c2, rb, 0);
    __builtin_amdgcn_sched_barrier(0);
    __builtin_amdgcn_s_barrier();
    MFMA_CLUSTER(4, 0)

    // ---- q3: R1 = stage B1(T+2) ; vmcnt(4) proves tile T+1 landed ----
    stageB(c2, rb, 1);
    asm volatile("s_waitcnt vmcnt(4)" ::: "memory");
    __builtin_amdgcn_sched_barrier(0);
    __builtin_amdgcn_s_barrier();
    MFMA_CLUSTER(4, 2)
  }

  // drain in-flight LDS-DMA before workgroup teardown
  asm volatile("s_waitcnt vmcnt(0)" ::: "memory");

  // ---- epilogue ----
  if constexpr (GELU) {
    uint16_t* hp = (uint16_t*)outp;
#pragma unroll
    for (int mi = 0; mi < 8; ++mi) {
#pragma unroll
      for (int ni = 0; ni < 4; ++ni) {
        const int col = n0 + (wn << 6) + (ni << 4) + fr;
#pragma unroll
        for (int j = 0; j < 4; ++j) {
          const int row = t0 + (wm << 7) + (mi << 4) + (fq << 2) + j;
          hp[((size_t)be * Ts + row) * NI + col] = f2bf(gelu_erf(acc[mi][ni][j]));
        }
      }
    }
  } else {
    float* op = (float*)outp;
#pragma unroll
    for (int mi = 0; mi < 8; ++mi) {
#pragma unroll
      for (int ni = 0; ni < 4; ++ni) {
        const int col = n0 + (wn << 6) + (ni << 4) + fr;
#pragma unroll
        for (int j = 0; j < 4; ++j) {
          const int row = t0 + (wm << 7) + (mi << 4) + (fq << 2) + j;
          op[((size_t)(t_start + row) * NE + be) * NH + col] = acc[mi][ni][j];
        }
      }
    }
  }
#undef MFMA_CLUSTER
}

extern "C" void kernel_launch(void* const* d_in, const int* in_sizes, int n_in,
                              void* d_out, int out_size, void* d_ws, size_t ws_size,
                              hipStream_t stream) {
  const float* x = (const float*)d_in[0];   // [T, E, H] fp32
  const float* wi = (const float*)d_in[1];  // [E, H, I] fp32
  const float* wo = (const float*)d_in[2];  // [E, I, H] fp32
  float* out = (float*)d_out;

  // ws: wiB bf16 [E][I][H] (64MiB) | woB bf16 [E][H][I] (64MiB) | xB | h
  uint16_t* wiB = (uint16_t*)d_ws;
  uint16_t* woB = (uint16_t*)((char*)d_ws + 67108864);
  char* rest = (char*)d_ws + 134217728;

  const size_t perRow = (size_t)NE * NH * 2 + (size_t)NE * NI * 2;  // 192 KiB
  size_t avail = (ws_size > 134217728u) ? ws_size - 134217728u : 0;
  int Ts = (int)(avail / perRow);
  Ts &= ~255;
  if (Ts > NT) Ts = NT;
  if (Ts < 256) Ts = 256;

  hipLaunchKernelGGL(conv_tr, dim3(NE, NH / 64, NI / 64), dim3(256), 0, stream,
                     wi, wiB, NH, NI);
  hipLaunchKernelGGL(conv_tr, dim3(NE, NI / 64, NH / 64), dim3(256), 0, stream,
                     wo, woB, NI, NH);

  for (int ts = 0; ts < NT; ts += Ts) {
    int cur = NT - ts;
    if (cur > Ts) cur = Ts;
    const int Mt = cur >> 8;
    uint16_t* xB = (uint16_t*)rest;
    uint16_t* h = (uint16_t*)(rest + (size_t)NE * cur * NH * 2);
    const int castGrid = (cur * NE * (NH / 8) + 255) / 256;
    hipLaunchKernelGGL(cast_x, dim3(castGrid < 2048 ? castGrid : 2048), dim3(256),
                       0, stream, x, xB, ts, cur);
    hipLaunchKernelGGL((k_mm<8, 4, NH, NH, true>), dim3(Mt * 4 * NE), dim3(512),
                       0, stream, xB, wiB, (void*)h, 0, cur);
    hipLaunchKernelGGL((k_mm<16, 2, NI, NI, false>), dim3(Mt * 2 * NE), dim3(512),
                       0, stream, h, woB, (void*)out, ts, cur);
  }
}

// Round 6
// 572.859 us; speedup vs baseline: 1.0996x; 1.0996x over previous
//
#include <hip/hip_runtime.h>
#include <stdint.h>

#define NE 64
#define NT 2048
#define NH 512
#define NI 1024

typedef __attribute__((ext_vector_type(8))) short bf16x8;
typedef __attribute__((ext_vector_type(4))) float f32x4;
typedef __attribute__((ext_vector_type(16))) float f32x16;

typedef const __attribute__((address_space(1))) void* gptr1_t;
typedef __attribute__((address_space(3))) void* lptr3_t;
#define GLOAD16(g, l) \
  __builtin_amdgcn_global_load_lds((gptr1_t)(const void*)(g), (lptr3_t)(void*)(l), 16, 0, 0)

static __device__ __forceinline__ uint16_t f2bf(float f) {
  uint32_t u = __builtin_bit_cast(uint32_t, f);
  u += 0x7fffu + ((u >> 16) & 1u);
  return (uint16_t)(u >> 16);
}

static __device__ __forceinline__ float gelu_erf(float v) {
  return 0.5f * v * (1.0f + erff(v * 0.7071067811865475f));
}

// ---------------------------------------------------------------------------
// cast_x: x[t_start+t][e][:] f32 -> xB[e][t][:] bf16
// ---------------------------------------------------------------------------
__global__ __launch_bounds__(256)
void cast_x(const float* __restrict__ x, uint16_t* __restrict__ xB,
            int t_start, int S) {
  const int total = S * NE * (NH / 8);
  for (int c = blockIdx.x * 256 + threadIdx.x; c < total; c += gridDim.x * 256) {
    const int hb = c & 63;
    const int e = (c >> 6) & 63;
    const int t = c >> 12;
    const float* ip = x + ((size_t)(t_start + t) * NE + e) * NH + (hb << 3);
    const f32x4 v0 = *(const f32x4*)ip;
    const f32x4 v1 = *(const f32x4*)(ip + 4);
    bf16x8 w;
#pragma unroll
    for (int u = 0; u < 4; ++u) {
      w[u] = (short)f2bf(v0[u]);
      w[u + 4] = (short)f2bf(v1[u]);
    }
    *(bf16x8*)&xB[((size_t)e * S + t) * NH + (hb << 3)] = w;
  }
}

// ---------------------------------------------------------------------------
// transpose + cast: in[e][K][N] f32 -> out[e][N][K] bf16, 64x64 tiles
// ---------------------------------------------------------------------------
__global__ __launch_bounds__(256)
void conv_tr(const float* __restrict__ in, uint16_t* __restrict__ out, int K, int N) {
  const int e = blockIdx.x;
  const int k0 = blockIdx.y << 6;
  const int n0 = blockIdx.z << 6;
  __shared__ uint16_t t[64][72];
  const int tid = threadIdx.x;
  const int r = tid >> 2;
  const int c0 = (tid & 3) << 4;
  const float* ip = in + ((size_t)e * K + k0 + r) * N + n0 + c0;
#pragma unroll
  for (int j = 0; j < 16; j += 4) {
    f32x4 v = *(const f32x4*)(ip + j);
#pragma unroll
    for (int u = 0; u < 4; ++u) t[c0 + j + u][r] = f2bf(v[u]);
  }
  __syncthreads();
  uint16_t* op = out + ((size_t)e * N + n0 + r) * K + k0 + c0;
  *(bf16x8*)op = *(const bf16x8*)&t[r][c0];
  *(bf16x8*)(op + 8) = *(const bf16x8*)&t[r][c0 + 8];
}

// ---------------------------------------------------------------------------
// GEMM1 + GELU: h[e,t,i] = gelu( xB[e,t,:] . wi'[e,i,:] ), bf16 out.
// m97 structure: 128x128x64 tile, single 32 KiB LDS buffer, 2 barriers/K-step,
// both operands staged via global_load_lds with XOR-swizzled SOURCE address
// (LDS dest linear). 4 waves (2x2), 4x4 16x16x32 MFMA per wave.
// LDS layout: elem (r,k) at r*64 + ((k>>3)^(r&7))*8 + (k&7).
// launch_bounds(256,4): VGPR=60 fits 64-budget; LDS 32KiB allows 5 blocks/CU.
// ---------------------------------------------------------------------------
__global__ __launch_bounds__(256, 4)
void k_gemm1(const uint16_t* __restrict__ xB, const uint16_t* __restrict__ wiB,
             uint16_t* __restrict__ h, int Ts) {
  const int Mt = Ts >> 7;
  const int nwg = gridDim.x;  // Mt*8*64, divisible by 8
  const int wid = (blockIdx.x & 7) * (nwg >> 3) + (blockIdx.x >> 3);
  const int bn = wid & 7;
  const int bm = (wid >> 3) % Mt;
  const int be = wid / (Mt << 3);
  const int t0 = bm << 7, n0 = bn << 7;

  __shared__ __align__(16) uint16_t As[8192];
  __shared__ __align__(16) uint16_t Bs[8192];

  const int tid = threadIdx.x, lane = tid & 63;
  const int wy = (tid >> 7) & 1, wx = (tid >> 6) & 1;

  const uint16_t* Abase = xB + ((size_t)be * Ts + t0) * NH;
  const uint16_t* Bbase = wiB + ((size_t)be * NI + n0) * NH;

  int off[4], ldsOff[4];
#pragma unroll
  for (int s = 0; s < 4; ++s) {
    const int c = (s << 8) + tid;
    const int rr = c >> 3, kgs = c & 7;
    off[s] = (rr << 9) + ((kgs ^ (rr & 7)) << 3);  // row stride NH=512
    ldsOff[s] = c << 4;
  }

  f32x4 acc[4][4];
#pragma unroll
  for (int i = 0; i < 4; ++i)
#pragma unroll
    for (int j = 0; j < 4; ++j) acc[i][j] = (f32x4){0.f, 0.f, 0.f, 0.f};

  const int KIT = NH >> 6;  // 8
  for (int it = 0; it < KIT; ++it) {
    __syncthreads();
#pragma unroll
    for (int s = 0; s < 4; ++s)
      GLOAD16(Abase + (it << 6) + off[s], (char*)As + ldsOff[s]);
#pragma unroll
    for (int s = 0; s < 4; ++s)
      GLOAD16(Bbase + (it << 6) + off[s], (char*)Bs + ldsOff[s]);
    __syncthreads();
#pragma unroll
    for (int ks = 0; ks < 2; ++ks) {
      const int kg = (ks << 2) + (lane >> 4);
      bf16x8 af[4], bfr[4];
#pragma unroll
      for (int mi = 0; mi < 4; ++mi) {
        const int row = (wy << 6) + (mi << 4) + (lane & 15);
        af[mi] = *(const bf16x8*)&As[(row << 6) + ((kg ^ (row & 7)) << 3)];
      }
#pragma unroll
      for (int ni = 0; ni < 4; ++ni) {
        const int col = (wx << 6) + (ni << 4) + (lane & 15);
        bfr[ni] = *(const bf16x8*)&Bs[(col << 6) + ((kg ^ (col & 7)) << 3)];
      }
#pragma unroll
      for (int mi = 0; mi < 4; ++mi)
#pragma unroll
        for (int ni = 0; ni < 4; ++ni)
          acc[mi][ni] = __builtin_amdgcn_mfma_f32_16x16x32_bf16(
              af[mi], bfr[ni], acc[mi][ni], 0, 0, 0);
    }
  }

#pragma unroll
  for (int mi = 0; mi < 4; ++mi) {
#pragma unroll
    for (int ni = 0; ni < 4; ++ni) {
      const int col = n0 + (wx << 6) + (ni << 4) + (lane & 15);
#pragma unroll
      for (int j = 0; j < 4; ++j) {
        const int r = t0 + (wy << 6) + (mi << 4) + ((lane >> 4) << 2) + j;
        h[((size_t)be * Ts + r) * NI + col] = f2bf(gelu_erf(acc[mi][ni][j]));
      }
    }
  }
}

// ---------------------------------------------------------------------------
// GEMM2: out[t,e,hc] = h[e,t,:] . wo'[e,hc,:], fp32 out. Same m97 staging but
// 32x32x16 MFMA (A/B arm): per wave 2x2 32x32 tiles; A row=lane&31,
// k-group=(lane>>5); C: col=lane&31, row=(reg&3)+8*(reg>>2)+4*(lane>>5).
// ---------------------------------------------------------------------------
__global__ __launch_bounds__(256, 4)
void k_gemm2(const uint16_t* __restrict__ hA, const uint16_t* __restrict__ woB,
             float* __restrict__ out, int t_start, int Ts) {
  const int Mt = Ts >> 7;
  const int nwg = gridDim.x;  // Mt*4*64
  const int wid = (blockIdx.x & 7) * (nwg >> 3) + (blockIdx.x >> 3);
  const int bn = wid & 3;
  const int bm = (wid >> 2) % Mt;
  const int be = wid / (Mt << 2);
  const int t0 = bm << 7, n0 = bn << 7;

  __shared__ __align__(16) uint16_t As[8192];
  __shared__ __align__(16) uint16_t Bs[8192];

  const int tid = threadIdx.x, lane = tid & 63;
  const int wy = (tid >> 7) & 1, wx = (tid >> 6) & 1;
  const int l31 = lane & 31, l5 = lane >> 5;

  const uint16_t* Abase = hA + ((size_t)be * Ts + t0) * NI;
  const uint16_t* Bbase = woB + ((size_t)be * NH + n0) * NI;

  int off[4], ldsOff[4];
#pragma unroll
  for (int s = 0; s < 4; ++s) {
    const int c = (s << 8) + tid;
    const int rr = c >> 3, kgs = c & 7;
    off[s] = (rr << 10) + ((kgs ^ (rr & 7)) << 3);  // row stride NI=1024
    ldsOff[s] = c << 4;
  }

  f32x16 acc[2][2];
#pragma unroll
  for (int i = 0; i < 2; ++i)
#pragma unroll
    for (int j = 0; j < 2; ++j)
#pragma unroll
      for (int u = 0; u < 16; ++u) acc[i][j][u] = 0.f;

  const int KIT = NI >> 6;  // 16
  for (int it = 0; it < KIT; ++it) {
    __syncthreads();
#pragma unroll
    for (int s = 0; s < 4; ++s)
      GLOAD16(Abase + (it << 6) + off[s], (char*)As + ldsOff[s]);
#pragma unroll
    for (int s = 0; s < 4; ++s)
      GLOAD16(Bbase + (it << 6) + off[s], (char*)Bs + ldsOff[s]);
    __syncthreads();
#pragma unroll
    for (int ks = 0; ks < 4; ++ks) {  // 4 k-steps of K=16
      const int kg = (ks << 1) + l5;  // 8-elem k-group index
      bf16x8 af[2], bfr[2];
#pragma unroll
      for (int mi = 0; mi < 2; ++mi) {
        const int row = (wy << 6) + (mi << 5) + l31;
        af[mi] = *(const bf16x8*)&As[(row << 6) + ((kg ^ (row & 7)) << 3)];
      }
#pragma unroll
      for (int ni = 0; ni < 2; ++ni) {
        const int col = (wx << 6) + (ni << 5) + l31;
        bfr[ni] = *(const bf16x8*)&Bs[(col << 6) + ((kg ^ (col & 7)) << 3)];
      }
#pragma unroll
      for (int mi = 0; mi < 2; ++mi)
#pragma unroll
        for (int ni = 0; ni < 2; ++ni)
          acc[mi][ni] = __builtin_amdgcn_mfma_f32_32x32x16_bf16(
              af[mi], bfr[ni], acc[mi][ni], 0, 0, 0);
    }
  }

  // epilogue: C row=(reg&3)+8*(reg>>2)+4*l5, col=l31 per 32x32 tile
#pragma unroll
  for (int mi = 0; mi < 2; ++mi) {
#pragma unroll
    for (int ni = 0; ni < 2; ++ni) {
      const int col = n0 + (wx << 6) + (ni << 5) + l31;
#pragma unroll
      for (int g = 0; g < 4; ++g) {
#pragma unroll
        for (int j = 0; j < 4; ++j) {
          const int row = t0 + (wy << 6) + (mi << 5) + (g << 3) + (l5 << 2) + j;
          out[((size_t)(t_start + row) * NE + be) * NH + col] =
              acc[mi][ni][(g << 2) + j];
        }
      }
    }
  }
}

extern "C" void kernel_launch(void* const* d_in, const int* in_sizes, int n_in,
                              void* d_out, int out_size, void* d_ws, size_t ws_size,
                              hipStream_t stream) {
  const float* x = (const float*)d_in[0];   // [T, E, H] fp32
  const float* wi = (const float*)d_in[1];  // [E, H, I] fp32
  const float* wo = (const float*)d_in[2];  // [E, I, H] fp32
  float* out = (float*)d_out;

  // ws: wiB bf16 [E][I][H] (64MiB) | woB bf16 [E][H][I] (64MiB) | xB | h
  uint16_t* wiB = (uint16_t*)d_ws;
  uint16_t* woB = (uint16_t*)((char*)d_ws + 67108864);
  char* rest = (char*)d_ws + 134217728;

  const size_t perRow = (size_t)NE * NH * 2 + (size_t)NE * NI * 2;  // 192 KiB
  size_t avail = (ws_size > 134217728u) ? ws_size - 134217728u : 0;
  int Ts = (int)(avail / perRow);
  Ts &= ~127;
  if (Ts > NT) Ts = NT;
  if (Ts < 128) Ts = 128;

  hipLaunchKernelGGL(conv_tr, dim3(NE, NH / 64, NI / 64), dim3(256), 0, stream,
                     wi, wiB, NH, NI);
  hipLaunchKernelGGL(conv_tr, dim3(NE, NI / 64, NH / 64), dim3(256), 0, stream,
                     wo, woB, NI, NH);

  for (int ts = 0; ts < NT; ts += Ts) {
    int cur = NT - ts;
    if (cur > Ts) cur = Ts;
    const int Mt = cur >> 7;
    uint16_t* xB = (uint16_t*)rest;
    uint16_t* h = (uint16_t*)(rest + (size_t)NE * cur * NH * 2);
    const int castGrid = (cur * NE * (NH / 8) + 255) / 256;
    hipLaunchKernelGGL(cast_x, dim3(castGrid < 2048 ? castGrid : 2048), dim3(256),
                       0, stream, x, xB, ts, cur);
    hipLaunchKernelGGL(k_gemm1, dim3(Mt * 8 * NE), dim3(256), 0, stream,
                       xB, wiB, h, cur);
    hipLaunchKernelGGL(k_gemm2, dim3(Mt * 4 * NE), dim3(256), 0, stream,
                       h, woB, out, ts, cur);
  }
}